// Round 5
// baseline (253.075 us; speedup 1.0000x reference)
//
#include <hip/hip_runtime.h>
#include <math.h>

#define NB 32          // batch
#define PP 24564       // priors
#define MM 32          // objects per image
#define NCLS 81
#define CHUNK 1024     // priors per k_match block
#define MBLK 24        // ceil(PP/CHUNK)
#define PPW 768        // posbit u32 words per image
#define POSX 64        // positive-loss blocks per image (block POSX = hardneg)
#define PROW (MBLK * CHUNK + MM)   // per-image plist row: 24 segments + forced extras

// ---- workspace layout (bytes); nothing needs pre-zeroing by the host ----
#define WS_ACC    0        // float[4]: 0=loc 1=ce 2=objpos 3=hardneg (zeroed by k_force)
#define WS_DONE   16       // int completion counter (zeroed by k_force)
#define WS_PCNT   32       // int[NB] total positives per image
#define WS_ECNT   160      // int[NB] forced-extra count per image
#define WS_CPART  288      // int[NB*MBLK] natural positives per segment
#define WS_FLIST  3456     // u32[NB*MM] forced prior per object
#define WS_BKEYP  8192     // u64[NB*MBLK*MM] per-block per-object best keys
#define WS_POSBIT 204800   // u32[NB*PPW] positive bitmask (fully rewritten each call)
#define WS_PLIST  303104   // u32[NB*PROW] compacted positives: p | (m<<16)

__device__ __forceinline__ float sl1(float d) {
    float a = fabsf(d);
    return a < 1.0f ? 0.5f * d * d : a - 0.5f;
}
__device__ __forceinline__ unsigned long long u64max(unsigned long long a, unsigned long long b) {
    return a > b ? a : b;
}

// ---------- Fused matching: per-prior + per-object argmax, segmented positive list ----------
extern "C" __global__ void __launch_bounds__(256) k_match(
    const float* __restrict__ priors,
    const float* __restrict__ boxes,
    unsigned long long* __restrict__ bkeyp,
    unsigned int* __restrict__ posbit,
    unsigned int* __restrict__ plist,
    int* __restrict__ cpart)
{
    const int n = blockIdx.y;
    const int t = threadIdx.x;
    const int lane = t & 63;
    const int wave = t >> 6;
    const int bx = blockIdx.x;
    const int p0 = bx * CHUNK;

    __shared__ float4 spri[CHUNK];                 // 16 KB
    __shared__ float bx0[MM], by0[MM], bx1[MM], by1[MM], bar_[MM];
    __shared__ unsigned long long wk[4][MM];
    __shared__ int bcnt;

#pragma unroll
    for (int i = 0; i < 4; i++) {
        int p = p0 + t + i * 256;
        float4 v;
        if (p < PP) v = *(const float4*)(priors + (size_t)p * 4);
        else { v.x = 3.f; v.y = 3.f; v.z = 3.5f; v.w = 3.5f; }   // dummy, iou=0
        spri[t + i * 256] = v;
    }
    if (t < MM) {
        const float* b = boxes + ((size_t)n * MM + t) * 4;
        float x1 = b[0], y1 = b[1], x2 = b[2], y2 = b[3];
        bx0[t] = x1; by0[t] = y1; bx1[t] = x2; by1[t] = y2;
        bar_[t] = (x2 - x1) * (y2 - y1);
    }
    if (t == 0) bcnt = 0;
    __syncthreads();

    float4 pr0 = spri[t], pr1 = spri[t + 256], pr2 = spri[t + 512], pr3 = spri[t + 768];
    const float pa0 = (pr0.z - pr0.x) * (pr0.w - pr0.y);
    const float pa1 = (pr1.z - pr1.x) * (pr1.w - pr1.y);
    const float pa2 = (pr2.z - pr2.x) * (pr2.w - pr2.y);
    const float pa3 = (pr3.z - pr3.x) * (pr3.w - pr3.y);
    unsigned pb0 = 0, pb1 = 0, pb2 = 0, pb3 = 0;   // per-prior keys: trunc-iou | (31-m)

#define DO_IOU(PR, PA, PB, ROFF) { \
        float w = fminf(x1, PR.z) - fmaxf(x0, PR.x); \
        float h = fminf(y1, PR.w) - fmaxf(y0, PR.y); \
        w = fmaxf(w, 0.0f); h = fmaxf(h, 0.0f); \
        float inter = w * h; \
        float iou = inter / (ar + PA - inter); \
        unsigned ib = __float_as_uint(iou); \
        unsigned nk = (ib & 0xFFFFFFE0u) | (unsigned)(31 - m); \
        PB = PB > nk ? PB : nk; \
        unsigned long long kk = ((unsigned long long)ib << 32) \
            | (unsigned long long)(0xFFFFFFFFu - (unsigned)(p0 + t + (ROFF))); \
        km = u64max(km, kk); }

#pragma unroll 2
    for (int m = 0; m < MM; m++) {
        const float x0 = bx0[m], y0 = by0[m], x1 = bx1[m], y1 = by1[m], ar = bar_[m];
        unsigned long long km = 0ULL;
        DO_IOU(pr0, pa0, pb0, 0)
        DO_IOU(pr1, pa1, pb1, 256)
        DO_IOU(pr2, pa2, pb2, 512)
        DO_IOU(pr3, pa3, pb3, 768)
#pragma unroll
        for (int d = 1; d < 64; d <<= 1)
            km = u64max(km, (unsigned long long)__shfl_xor(km, d));
        if (lane == 0) wk[wave][m] = km;
    }
#undef DO_IOU

    // per-prior outputs: positive bits (plain stores) + segment-compacted entries
    const unsigned long long lm = (1ULL << lane) - 1ULL;
    unsigned long long bl[4]; bool pf[4]; unsigned pv[4]; int cw[4];
#define ROWOUT(PB, R) { \
        int p = p0 + t + (R) * 256; \
        bool pos = (PB >= 0x3F000000u) && (p < PP); \
        unsigned long long ball = __ballot(pos); \
        if (lane == 0) { \
            int wi = n * PPW + ((p0 + (R) * 256 + wave * 64) >> 5); \
            posbit[wi] = (unsigned)ball; posbit[wi + 1] = (unsigned)(ball >> 32); \
        } \
        bl[R] = ball; pf[R] = pos; cw[R] = __popcll(ball); \
        pv[R] = (unsigned)p | ((31u - (PB & 31u)) << 16); }
    ROWOUT(pb0, 0) ROWOUT(pb1, 1) ROWOUT(pb2, 2) ROWOUT(pb3, 3)
#undef ROWOUT

    int tot = cw[0] + cw[1] + cw[2] + cw[3];
    int wbase = 0;
    if (lane == 0 && tot) wbase = atomicAdd(&bcnt, tot);   // LDS, per-wave
    wbase = __shfl(wbase, 0);
    unsigned* pl = plist + (size_t)n * PROW + (size_t)bx * CHUNK;
    int b = wbase;
#pragma unroll
    for (int r = 0; r < 4; r++) {
        if (pf[r]) pl[b + __popcll(bl[r] & lm)] = pv[r];
        b += cw[r];
    }

    __syncthreads();
    if (t == 0) cpart[n * MBLK + bx] = bcnt;
    if (t < MM) {
        unsigned long long r = u64max(u64max(wk[0][t], wk[1][t]),
                                      u64max(wk[2][t], wk[3][t]));
        bkeyp[((size_t)n * MBLK + bx) * MM + t] = r;      // plain store, distinct slot
    }
}

// ---------- Forced overrides + totals + accumulator zeroing (1 block) ----------
extern "C" __global__ void __launch_bounds__(1024) k_force(
    const unsigned long long* __restrict__ bkeyp,
    const int* __restrict__ cpart,
    unsigned int* __restrict__ flist,
    unsigned int* __restrict__ posbit,
    unsigned int* __restrict__ plist,
    int* __restrict__ pcnt,
    int* __restrict__ ecnt,
    float* __restrict__ acc,
    int* __restrict__ done)
{
    const int t = threadIdx.x;          // 1024 = NB*MM
    __shared__ int lecnt[NB];
    if (t < NB) lecnt[t] = 0;
    if (t < 4) acc[t] = 0.f;
    if (t == 4) *done = 0;
    __syncthreads();

    const int n = t >> 5, m = t & 31;
    const unsigned long long* bp = bkeyp + ((size_t)n * MBLK) * MM + m;
    unsigned long long r = 0ULL;
#pragma unroll
    for (int s = 0; s < MBLK; s++) r = u64max(r, bp[(size_t)s * MM]);
    unsigned p = 0xFFFFFFFFu - (unsigned)(r & 0xFFFFFFFFULL);
    flist[t] = p;
    unsigned bit = 1u << (p & 31);
    unsigned old = atomicOr(&posbit[n * PPW + (p >> 5)], bit);
    if (!(old & bit)) {                 // not already positive: append to extras
        int slot = atomicAdd(&lecnt[n], 1);
        plist[(size_t)n * PROW + MBLK * CHUNK + slot] = p | ((unsigned)m << 16);
    }
    __syncthreads();
    if (t < NB) {
        int e = lecnt[t];
        ecnt[t] = e;
        int tot2 = e;
        for (int b = 0; b < MBLK; b++) tot2 += cpart[t * MBLK + b];
        pcnt[t] = tot2;
    }
}

// ---------- Fused positive losses + hard-negative mining + finalize ----------
extern "C" __global__ void __launch_bounds__(256) k_posneg(
    const float* __restrict__ pred_boxes,
    const float* __restrict__ pred_cls,
    const float* __restrict__ pred_obj,
    const float* __restrict__ priors,
    const float* __restrict__ boxes,
    const int* __restrict__ labels,
    const unsigned int* __restrict__ plist,
    const unsigned int* __restrict__ flist,
    const unsigned int* __restrict__ posbit,
    const int* __restrict__ cpart,
    const int* __restrict__ ecnt,
    const int* __restrict__ pcnt,
    float* __restrict__ acc,
    int* __restrict__ done,
    float* __restrict__ out)
{
    const int n = blockIdx.y;
    const int t = threadIdx.x;
    const int lane = t & 63;
    const int wave = t >> 6;

    __shared__ unsigned fl[MM];
    __shared__ int pref[MBLK + 2];
    __shared__ float sacc[4];
    __shared__ unsigned int hist[4][256];
    __shared__ unsigned int hsum[256];
    __shared__ unsigned int s_prefix;
    __shared__ int s_rem;
    __shared__ float wsum[4], wcnt[4];

    if (t < MM) fl[t] = flist[n * MM + t];
    if (t < 4) sacc[t] = 0.f;
    if (t == 0) {
        int a = 0;
        for (int s = 0; s < MBLK; s++) { pref[s] = a; a += cpart[n * MBLK + s]; }
        pref[MBLK] = a;
        pref[MBLK + 1] = a + ecnt[n];
    }
    __syncthreads();
    const int T = pref[MBLK + 1];

    if (blockIdx.x < POSX) {
        // ---- positive-prior losses: one wave per positive ----
        const unsigned* pl = plist + (size_t)n * PROW;
        float ce_s = 0.f, loc_s = 0.f, op_s = 0.f;
        for (int i = blockIdx.x * 4 + wave; i < T; i += POSX * 4) {
            int s = 0;
            while (pref[s + 1] <= i) s++;               // wave-uniform, <=25 iters
            int slot = (s < MBLK) ? s * CHUNK + (i - pref[s])
                                  : MBLK * CHUNK + (i - pref[MBLK]);
            const unsigned e = pl[slot];
            const int p = (int)(e & 0xFFFFu);
            int bm = (int)((e >> 16) & 31u);
#pragma unroll
            for (int j = 0; j < MM; j++)
                if (fl[j] == (unsigned)p) bm = j;       // ascending j = last-wins
            const size_t idx = (size_t)n * PP + p;

            const float* row = pred_cls + idx * NCLS;
            float a = row[lane];
            float b = (lane < NCLS - 64) ? row[lane + 64] : -INFINITY;
            float mx = fmaxf(a, b);
#pragma unroll
            for (int d = 1; d < 64; d <<= 1) mx = fmaxf(mx, __shfl_xor(mx, d));
            float se = expf(a - mx) + ((lane < NCLS - 64) ? expf(b - mx) : 0.f);
#pragma unroll
            for (int d = 1; d < 64; d <<= 1) se += __shfl_xor(se, d);

            if (lane == 0) {
                int lb = labels[n * MM + bm];
                ce_s += mx + logf(se) - row[lb];
            } else if (lane == 1) {
                float4 pb = *(const float4*)(priors + (size_t)p * 4);
                const float* bb = boxes + ((size_t)n * MM + bm) * 4;
                float gx1 = bb[0], gy1 = bb[1], gx2 = bb[2], gy2 = bb[3];
                float pcx = (pb.x + pb.z) * 0.5f, pcy = (pb.y + pb.w) * 0.5f;
                float pw = pb.z - pb.x, ph = pb.w - pb.y;
                float g0 = ((gx1 + gx2) * 0.5f - pcx) / (pw / 10.0f);
                float g1 = ((gy1 + gy2) * 0.5f - pcy) / (ph / 10.0f);
                float g2 = logf((gx2 - gx1) / pw) * 5.0f;
                float g3 = logf((gy2 - gy1) / ph) * 5.0f;
                float4 pd = *(const float4*)(pred_boxes + idx * 4);
                loc_s += sl1(pd.x - g0) + sl1(pd.y - g1) + sl1(pd.z - g2) + sl1(pd.w - g3);
            } else if (lane == 2) {
                float o = pred_obj[idx];
                op_s += (o - 1.0f) * (o - 1.0f);
            }
        }
        if (lane == 0 && ce_s != 0.f)  atomicAdd(&sacc[0], ce_s);
        if (lane == 1 && loc_s != 0.f) atomicAdd(&sacc[1], loc_s);
        if (lane == 2 && op_s != 0.f)  atomicAdd(&sacc[2], op_s);
        __syncthreads();
        if (t == 0) {
            if (sacc[0] != 0.f) atomicAdd(&acc[1], sacc[0]);
            if (sacc[1] != 0.f) atomicAdd(&acc[0], sacc[1]);
            if (sacc[2] != 0.f) atomicAdd(&acc[2], sacc[2]);
        }
    } else {
        // ---- hard-negative mining for image n (single block, 4 waves) ----
        int k = T * 3;
        if (k > PP) k = PP;
        const float* obj = pred_obj + (size_t)n * PP;
        const unsigned int* pbits = posbit + n * PPW;

        if (k >= PP) {
            float s = 0.f;
            for (int p = t; p < PP; p += 256) {
                unsigned msk = (pbits[p >> 5] >> (p & 31)) & 1u;
                float o = obj[p];
                s += msk ? 0.f : o * o;
            }
#pragma unroll
            for (int d = 32; d > 0; d >>= 1) s += __shfl_down(s, d);
            if ((t & 63) == 0) wsum[wave] = s;
            __syncthreads();
            if (t == 0)
                atomicAdd(&acc[3], wsum[0] + wsum[1] + wsum[2] + wsum[3]);
        } else if (k > 0) {
            unsigned prefix = 0; int rem = k;
            for (int pass = 0; pass < 4; ++pass) {
                const int shift = 24 - 8 * pass;
                for (int i = t; i < 4 * 256; i += 256) ((unsigned*)hist)[i] = 0;
                __syncthreads();
                for (int p = t; p < PP; p += 256) {
                    unsigned msk = (pbits[p >> 5] >> (p & 31)) & 1u;
                    float o = obj[p];
                    float v = msk ? 0.f : o * o;
                    unsigned bb2 = __float_as_uint(v);
                    if (pass == 0 || (bb2 >> (shift + 8)) == prefix)
                        atomicAdd(&hist[wave][(bb2 >> shift) & 0xFFu], 1u);
                }
                __syncthreads();
                if (t < 256)
                    hsum[t] = hist[0][t] + hist[1][t] + hist[2][t] + hist[3][t];
                __syncthreads();
                if (t == 0) {
                    unsigned cum = 0; int d;
                    for (d = 255; d > 0; --d) {
                        if (cum + hsum[d] >= (unsigned)rem) break;
                        cum += hsum[d];
                    }
                    s_prefix = (prefix << 8) | (unsigned)d;
                    s_rem = rem - (int)cum;
                }
                __syncthreads();
                prefix = s_prefix; rem = s_rem;
                __syncthreads();
            }
            const unsigned thr = prefix;
            const float thrv = __uint_as_float(thr);
            float mysum = 0.f, mycnt = 0.f;
            for (int p = t; p < PP; p += 256) {
                unsigned msk = (pbits[p >> 5] >> (p & 31)) & 1u;
                float o = obj[p];
                float v = msk ? 0.f : o * o;
                if (__float_as_uint(v) > thr) { mysum += v; mycnt += 1.f; }
            }
#pragma unroll
            for (int d = 32; d > 0; d >>= 1) {
                mysum += __shfl_down(mysum, d);
                mycnt += __shfl_down(mycnt, d);
            }
            if ((t & 63) == 0) { wsum[wave] = mysum; wcnt[wave] = mycnt; }
            __syncthreads();
            if (t == 0) {
                float ts = wsum[0] + wsum[1] + wsum[2] + wsum[3];
                float tc = wcnt[0] + wcnt[1] + wcnt[2] + wcnt[3];
                atomicAdd(&acc[3], ts + ((float)k - tc) * thrv);
            }
        }
    }

    // ---- completion: last of the (POSX+1)*NB blocks finalizes ----
    if (t == 0) {
        __threadfence();
        int old = atomicAdd(done, 1);
        if (old == (POSX + 1) * NB - 1) {
            float a0 = atomicAdd(&acc[0], 0.f);
            float a1 = atomicAdd(&acc[1], 0.f);
            float a2 = atomicAdd(&acc[2], 0.f);
            float a3 = atomicAdd(&acc[3], 0.f);
            int np = 0, den = 0;
            for (int i = 0; i < NB; i++) {
                int c = pcnt[i];
                np += c;
                int kk = c * 3; if (kk > PP) kk = PP;
                den += kk;
            }
            float npf = (float)np;
            out[0] = a1 / npf + a2 / npf
                   + a3 / fmaxf((float)den, 1.0f)
                   + a0 / (npf * 4.0f);
        }
    }
}

extern "C" void kernel_launch(void* const* d_in, const int* in_sizes, int n_in,
                              void* d_out, int out_size, void* d_ws, size_t ws_size,
                              hipStream_t stream) {
    const float* pred_boxes = (const float*)d_in[0];
    const float* pred_cls   = (const float*)d_in[1];
    const float* pred_obj   = (const float*)d_in[2];
    const float* priors     = (const float*)d_in[3];
    const float* boxes      = (const float*)d_in[4];
    const int*   labels     = (const int*)d_in[5];

    char* ws = (char*)d_ws;
    float* acc = (float*)(ws + WS_ACC);
    int* done  = (int*)(ws + WS_DONE);
    int* pcnt  = (int*)(ws + WS_PCNT);
    int* ecnt  = (int*)(ws + WS_ECNT);
    int* cpart = (int*)(ws + WS_CPART);
    unsigned int* flist = (unsigned int*)(ws + WS_FLIST);
    unsigned long long* bkeyp = (unsigned long long*)(ws + WS_BKEYP);
    unsigned int* posbit = (unsigned int*)(ws + WS_POSBIT);
    unsigned int* plist = (unsigned int*)(ws + WS_PLIST);

    k_match<<<dim3(MBLK, NB), 256, 0, stream>>>(priors, boxes, bkeyp, posbit, plist, cpart);
    k_force<<<1, 1024, 0, stream>>>(bkeyp, cpart, flist, posbit, plist, pcnt, ecnt, acc, done);
    k_posneg<<<dim3(POSX + 1, NB), 256, 0, stream>>>(pred_boxes, pred_cls, pred_obj,
                                                     priors, boxes, labels, plist, flist,
                                                     posbit, cpart, ecnt, pcnt, acc, done,
                                                     (float*)d_out);
}